// Round 4
// baseline (88.379 us; speedup 1.0000x reference)
//
#include <hip/hip_runtime.h>
#include <math.h>

#define SLEN 53
#define NPIX 2809
#define NPARAM 12
#define BLK 256
#define PW 16          // per-tile param stride in ws (floats)
#define NSLOT 11       // ceil(2809/256)

// Fast atan: 2-step Cephes range reduction + deg-4 poly in x^2. err ~2e-7.
__device__ __forceinline__ float fast_atan(float u) {
    float t = __builtin_fabsf(u);
    float rin = __builtin_amdgcn_rcpf(t);
    bool big = t > 1.0f;
    float w = big ? rin : t;
    bool mid = w > 0.4142135624f;
    float w2 = (w - 1.0f) * __builtin_amdgcn_rcpf(w + 1.0f);
    float x = mid ? w2 : w;
    float z = x * x;
    float p = ((8.05374449538e-2f * z - 1.38776856032e-1f) * z
               + 1.99777106478e-1f) * z - 3.33329491539e-1f;
    float r = __builtin_fmaf(p * z, x, x);
    r = mid ? r + 0.78539816339744831f : r;
    r = big ? 1.57079632679489662f - r : r;
    return __builtin_copysignf(r, u);
}

// atanh(v) = 0.5*ln2*log2((1+v)*rcp(1-v)); |v|<=0.995 so 1-v is exact.
__device__ __forceinline__ float fast_atanh(float v) {
    float a = __builtin_fabsf(v);
    float t = (1.0f + a) * __builtin_amdgcn_rcpf(1.0f - a);
    float r = 0.34657359027997264f * __builtin_amdgcn_logf(t);
    return __builtin_copysignf(r, v);
}

// One thread per tile: all per-tile transcendentals/divides done ONCE here
// instead of by every wave of every block in the hot kernel.
__global__ __launch_bounds__(BLK) void prep_kernel(
    const float* __restrict__ lens_params,
    const float* __restrict__ bools,
    float* __restrict__ ws, int n_tiles)
{
    int t = blockIdx.x * blockDim.x + threadIdx.x;
    if (t >= n_tiles) return;
    const float* p = lens_params + t * NPARAM;
    const float bl   = bools[t];
    const float flux = p[0] * 1000.0f + 100.0f;
    const float sg   = p[3] * 3.0f + 1.0f;
    const float s2   = sg * sg;
    const float A    = bl * flux / (6.28318530717958647692f * s2);
    const float nh2  = -0.5f / s2 * 1.44269504088896340736f;   // exp2 coeff
    const float b  = p[7], cx = p[8], cy = p[9], e1 = p[10], e2 = p[11];
    const float ell  = sqrtf(e1 * e1 + e2 * e2);
    const float q    = (1.0f - ell) / (1.0f + ell);
    const float qinv = 1.0f / q;
    const float ph   = atanf(e2 / e1);
    const float cosp = cosf(ph), sinp = sinf(ph);
    const float qf   = sqrtf(qinv - q);
    const float safe = fmaxf(qf, 0.001f);
    const float bos  = b / safe;
    float* w = ws + t * PW;
    w[0]  = bl;   w[1]  = A;    w[2]  = nh2;  w[3]  = cosp;
    w[4]  = sinp; w[5]  = q;    w[6]  = qinv; w[7]  = safe;
    w[8]  = bos;  w[9]  = cx;   w[10] = cy;   w[11] = b;
    w[12] = (qf >= 0.001f) ? 1.0f : 0.0f;     // main_branch (always 1 for this data)
    w[13] = 0.0f; w[14] = 0.0f; w[15] = 0.0f;
}

template<bool MB>
__device__ __forceinline__ void run_tile(
    float* __restrict__ outp, int tid,
    const float* __restrict__ Ctab, const float* __restrict__ Etab,
    float A, float cosp, float sinp, float q, float qinv,
    float safe, float bos, float cx, float cy, float b)
{
    #pragma unroll
    for (int g = 0; g < 3; ++g) {
        const int nk = (g == 2) ? 3 : 4;      // slots 0..10
        float xc[4], yc[4], val[4];
        // phase A: issue all coord LDS reads for the batch
        #pragma unroll
        for (int k = 0; k < 4; ++k) {
            if (k >= nk) break;
            const int slot = g * 4 + k;
            int idx = slot * BLK + tid;
            if (slot == NSLOT - 1) idx = min(idx, NPIX - 1); // keep tables in-bounds
            const unsigned i = ((unsigned)idx * 39569u) >> 21;  // idx/53, exact for idx<419430
            const int j = idx - (int)i * 53;
            xc[k] = Ctab[j];
            yc[k] = Ctab[i];
        }
        // phase B: 4 independent math chains
        #pragma unroll
        for (int k = 0; k < 4; ++k) {
            if (k >= nk) break;
            const float dx = xc[k] - cx, dy = yc[k] - cy;
            const float xsie = dx * cosp + dy * sinp;
            const float ysie = dy * cosp - dx * sinp;
            const float arg = __builtin_fmaf(q * xsie, xsie,
                              __builtin_fmaf(qinv * ysie, ysie, 1e-12f));
            const float rcp_r = __builtin_amdgcn_rsqf(arg);   // 1/r_ell
            float xtg, ytg;
            if (MB) {
                xtg = bos * fast_atan(safe * xsie * rcp_r);
                ytg = bos * fast_atanh(safe * ysie * rcp_r);
            } else {
                xtg = b * xsie * rcp_r;
                ytg = b * ysie * rcp_r;
            }
            const float xg = xtg * cosp - ytg * sinp;
            const float yg = ytg * cosp + xtg * sinp;
            const float xs = (xc[k] - xg) + 26.0f;
            const float ys = (yc[k] - yg) + 26.0f;
            const float fx = __builtin_floorf(xs);
            const float fy = __builtin_floorf(ys);
            const float x0f = fminf(fmaxf(fx, 0.0f), 52.0f);
            const float x1f = fminf(fmaxf(fx + 1.0f, 0.0f), 52.0f);
            const float y0f = fminf(fmaxf(fy, 0.0f), 52.0f);
            const float y1f = fminf(fmaxf(fy + 1.0f, 0.0f), 52.0f);
            const int x0 = (int)x0f, x1 = (int)x1f;
            const int y0 = (int)y0f, y1 = (int)y1f;
            // separable bilinear of the Gaussian
            const float Fx = (x1f - xs) * Etab[x0] + (xs - x0f) * Etab[x1];
            const float Fy = (y1f - ys) * Etab[y0] + (ys - y0f) * Etab[y1];
            val[k] = A * Fx * Fy;
        }
        // phase C: coalesced stores
        #pragma unroll
        for (int k = 0; k < 4; ++k) {
            if (k >= nk) break;
            const int slot = g * 4 + k;
            const int idx = slot * BLK + tid;
            if (slot < NSLOT - 1 || idx < NPIX) outp[idx] = val[k];
        }
    }
}

__global__ __launch_bounds__(BLK) void lgtd_kernel(
    const float* __restrict__ ws,
    float* __restrict__ out)
{
    const int tile = blockIdx.x;
    const float* w = ws + tile * PW;   // uniform addr -> s_loads
    float* outp = out + (size_t)tile * NPIX;
    const int tid = threadIdx.x;

    const float bl = w[0];
    if (bl == 0.0f) {                  // block-uniform: safe early return (before barrier)
        #pragma unroll
        for (int s = 0; s < NSLOT; ++s) {
            const int idx = s * BLK + tid;
            if (s < NSLOT - 1 || idx < NPIX) outp[idx] = 0.0f;
        }
        return;
    }

    const float A    = w[1],  nh2  = w[2],  cosp = w[3], sinp = w[4];
    const float q    = w[5],  qinv = w[6],  safe = w[7], bos  = w[8];
    const float cx   = w[9],  cy   = w[10], b    = w[11];
    const bool  mb   = (w[12] != 0.0f);

    __shared__ float Ctab[SLEN];   // exact ref coords: 53*k/52 - 27
    __shared__ float Etab[SLEN];   // exp2(nh2*(k-26)^2)
    if (tid < SLEN) {
        const float kf = (float)tid;
        Ctab[tid] = 53.0f * kf / 52.0f - 27.0f;
        const float d = kf - 26.0f;
        Etab[tid] = __builtin_amdgcn_exp2f(nh2 * (d * d));
    }
    __syncthreads();

    if (mb)
        run_tile<true >(outp, tid, Ctab, Etab, A, cosp, sinp, q, qinv, safe, bos, cx, cy, b);
    else
        run_tile<false>(outp, tid, Ctab, Etab, A, cosp, sinp, q, qinv, safe, bos, cx, cy, b);
}

extern "C" void kernel_launch(void* const* d_in, const int* in_sizes, int n_in,
                              void* d_out, int out_size, void* d_ws, size_t ws_size,
                              hipStream_t stream) {
    const float* lens  = (const float*)d_in[0];  // (N, 1, 12) fp32
    const float* bools = (const float*)d_in[1];  // (N, 1, 1)  fp32
    float* out = (float*)d_out;                  // (N, 1, 1, 53, 53) fp32
    float* ws  = (float*)d_ws;                   // n_tiles*PW floats (256 KB)
    const int n_tiles = in_sizes[1];
    prep_kernel<<<(n_tiles + BLK - 1) / BLK, BLK, 0, stream>>>(lens, bools, ws, n_tiles);
    lgtd_kernel<<<n_tiles, BLK, 0, stream>>>(ws, out);
}

// Round 5
// 87.938 us; speedup vs baseline: 1.0050x; 1.0050x over previous
//
#include <hip/hip_runtime.h>
#include <math.h>

#define SLEN 53
#define NPIX 2809
#define NPARAM 12
#define BLK 256
#define PW 16          // per-tile param stride in ws (floats)

// atan on full range: reciprocal reduction to [0,1] + 6-term minimax poly
// in x^2. Max abs err ~1e-5 rad -> value err <= ~0.1 (threshold 2.94).
__device__ __forceinline__ float fast_atan(float u) {
    float t = __builtin_fabsf(u);
    float rin = __builtin_amdgcn_rcpf(t);
    bool big = t > 1.0f;
    float w = big ? rin : t;                 // [0,1]
    float z = w * w;
    float p = -0.01172120f;
    p = __builtin_fmaf(p, z,  0.05265332f);
    p = __builtin_fmaf(p, z, -0.11643287f);
    p = __builtin_fmaf(p, z,  0.19354346f);
    p = __builtin_fmaf(p, z, -0.33262347f);
    p = __builtin_fmaf(p, z,  0.99997726f);
    float r = w * p;
    r = big ? 1.57079632679489662f - r : r;
    return __builtin_copysignf(r, u);
}

// atanh(v) = 0.5*ln2*log2((1+v)*rcp(1-v)); |v| <= sqrt(1-q^2) <= 0.995.
__device__ __forceinline__ float fast_atanh(float v) {
    float a = __builtin_fabsf(v);
    float t = (1.0f + a) * __builtin_amdgcn_rcpf(1.0f - a);
    float r = 0.34657359027997264f * __builtin_amdgcn_logf(t);
    return __builtin_copysignf(r, v);
}

// One thread per tile: all per-tile transcendentals/divides done ONCE.
__global__ __launch_bounds__(BLK) void prep_kernel(
    const float* __restrict__ lens_params,
    const float* __restrict__ bools,
    float* __restrict__ ws, int n_tiles)
{
    int t = blockIdx.x * blockDim.x + threadIdx.x;
    if (t >= n_tiles) return;
    const float* p = lens_params + t * NPARAM;
    const float bl   = bools[t];
    const float flux = p[0] * 1000.0f + 100.0f;
    const float sg   = p[3] * 3.0f + 1.0f;
    const float s2   = sg * sg;
    const float A    = bl * flux / (6.28318530717958647692f * s2);
    const float nh2  = -0.5f / s2 * 1.44269504088896340736f;   // exp2 coeff
    const float b  = p[7], cx = p[8], cy = p[9], e1 = p[10], e2 = p[11];
    const float ell  = sqrtf(e1 * e1 + e2 * e2);
    const float q    = (1.0f - ell) / (1.0f + ell);
    const float qinv = 1.0f / q;
    const float ph   = atanf(e2 / e1);
    const float cosp = cosf(ph), sinp = sinf(ph);
    const float qf   = sqrtf(qinv - q);
    const float safe = fmaxf(qf, 0.001f);
    const float bos  = b / safe;
    float* w = ws + t * PW;
    w[0]  = bl;   w[1]  = A;    w[2]  = nh2;  w[3]  = cosp;
    w[4]  = sinp; w[5]  = q;    w[6]  = qinv; w[7]  = safe;
    w[8]  = bos;  w[9]  = cx;   w[10] = cy;   w[11] = b;
    w[12] = (qf >= 0.001f) ? 1.0f : 0.0f;     // main_branch
    w[13] = 0.0f; w[14] = 0.0f; w[15] = 0.0f;
}

// Row-per-wave mapping: lane = column (lane<53), wave w handles rows
// w, w+4, w+8, ... All x-dependent terms hoisted out of the row loop.
template<bool MB>
__device__ __forceinline__ void run_tile(
    float* __restrict__ outp, int lane, int wv, const float* __restrict__ Etab,
    const float* __restrict__ Ctab,
    float A, float cosp, float sinp, float q, float qinv,
    float safe, float bos, float cx, float cy, float b)
{
    // per-lane invariants (53 rows share these)
    const float xcl  = Ctab[lane];
    const float dx   = xcl - cx;
    const float dxc  = dx * cosp;
    const float dxs  = dx * sinp;
    const float xc26 = xcl + 26.0f;

    for (int r = wv; r < SLEN; r += 4) {
        // per-row wave-uniform terms (broadcast LDS read)
        const float ycr  = Ctab[r];
        const float dy   = ycr - cy;
        const float t1   = dy * sinp;
        const float t2   = dy * cosp;
        const float yc26 = ycr + 26.0f;

        const float xsie = dxc + t1;          // (x-cx)cosp + (y-cy)sinp
        const float ysie = t2 - dxs;          // (y-cy)cosp - (x-cx)sinp
        const float arg  = __builtin_fmaf(q * xsie, xsie,
                           __builtin_fmaf(qinv * ysie, ysie, 1e-12f));
        const float rcp_r = __builtin_amdgcn_rsqf(arg);   // 1/r_ell
        float xtg, ytg;
        if (MB) {
            xtg = bos * fast_atan(safe * xsie * rcp_r);
            ytg = bos * fast_atanh(safe * ysie * rcp_r);
        } else {
            xtg = b * xsie * rcp_r;
            ytg = b * ysie * rcp_r;
        }
        const float xg = xtg * cosp - ytg * sinp;
        const float yg = ytg * cosp + xtg * sinp;
        const float xs = xc26 - xg;
        const float ys = yc26 - yg;
        const float fx = __builtin_floorf(xs);
        const float fy = __builtin_floorf(ys);
        const float x0f = fminf(fmaxf(fx,        0.0f), 52.0f);  // v_med3
        const float x1f = fminf(fmaxf(fx + 1.0f, 0.0f), 52.0f);
        const float y0f = fminf(fmaxf(fy,        0.0f), 52.0f);
        const float y1f = fminf(fmaxf(fy + 1.0f, 0.0f), 52.0f);
        const int x0 = (int)x0f, x1 = (int)x1f;
        const int y0 = (int)y0f, y1 = (int)y1f;
        // separable bilinear of the Gaussian
        const float Fx = (x1f - xs) * Etab[x0] + (xs - x0f) * Etab[x1];
        const float Fy = (y1f - ys) * Etab[y0] + (ys - y0f) * Etab[y1];
        outp[r * SLEN + lane] = A * Fx * Fy;
    }
}

__global__ __launch_bounds__(BLK) void lgtd_kernel(
    const float* __restrict__ ws,
    float* __restrict__ out)
{
    const int tile = blockIdx.x;
    const float* w = ws + tile * PW;   // uniform addr -> s_loads
    float* outp = out + (size_t)tile * NPIX;
    const int tid = threadIdx.x;

    const float bl = w[0];
    if (bl == 0.0f) {                  // block-uniform early path (pre-barrier)
        #pragma unroll
        for (int s = 0; s < 11; ++s) {
            const int idx = s * BLK + tid;
            if (s < 10 || idx < NPIX) outp[idx] = 0.0f;
        }
        return;
    }

    const float A    = w[1],  nh2  = w[2],  cosp = w[3], sinp = w[4];
    const float q    = w[5],  qinv = w[6],  safe = w[7], bos  = w[8];
    const float cx   = w[9],  cy   = w[10], b    = w[11];
    const bool  mb   = (w[12] != 0.0f);

    __shared__ float Ctab[SLEN];   // exact ref coords: 53*k/52 - 27
    __shared__ float Etab[SLEN];   // exp2(nh2*(k-26)^2)
    if (tid < SLEN) {
        const float kf = (float)tid;
        Ctab[tid] = 53.0f * kf / 52.0f - 27.0f;
        const float d = kf - 26.0f;
        Etab[tid] = __builtin_amdgcn_exp2f(nh2 * (d * d));
    }
    __syncthreads();

    const int lane = tid & 63;
    const int wv   = tid >> 6;
    if (lane >= SLEN) return;      // no barriers after this point

    if (mb)
        run_tile<true >(outp, lane, wv, Etab, Ctab, A, cosp, sinp, q, qinv, safe, bos, cx, cy, b);
    else
        run_tile<false>(outp, lane, wv, Etab, Ctab, A, cosp, sinp, q, qinv, safe, bos, cx, cy, b);
}

extern "C" void kernel_launch(void* const* d_in, const int* in_sizes, int n_in,
                              void* d_out, int out_size, void* d_ws, size_t ws_size,
                              hipStream_t stream) {
    const float* lens  = (const float*)d_in[0];  // (N, 1, 12) fp32
    const float* bools = (const float*)d_in[1];  // (N, 1, 1)  fp32
    float* out = (float*)d_out;                  // (N, 1, 1, 53, 53) fp32
    float* ws  = (float*)d_ws;                   // n_tiles*PW floats (256 KB)
    const int n_tiles = in_sizes[1];
    prep_kernel<<<(n_tiles + BLK - 1) / BLK, BLK, 0, stream>>>(lens, bools, ws, n_tiles);
    lgtd_kernel<<<n_tiles, BLK, 0, stream>>>(ws, out);
}